// Round 2
// baseline (165.313 us; speedup 1.0000x reference)
//
#include <hip/hip_runtime.h>

// out[(j*f + c)*m + q] = yd[idx[q*K + j]*f + c]
// m=8192, f=512, K=8, fp32. Memory-bound gather+transpose.
//
// Strategy: block = (q-tile of Q=16, one j). Stage the Q gathered rows
// (full f columns) into LDS via coalesced float4 loads (each row read once
// globally), then write the transpose with lanes along q (coalesced 4B/lane,
// 64B segments). LDS row stride f+1 -> bank=(q+c)%32, <=2-way (free).

#define QTILE 16
#define THREADS 256

__global__ __launch_bounds__(THREADS) void gather_transpose_kernel(
    const float* __restrict__ yd, const int* __restrict__ idx,
    float* __restrict__ out, int m, int f, int k)
{
    const int qbase = blockIdx.x * QTILE;
    const int j = blockIdx.y;
    const int t = threadIdx.x;
    const int ldst = f + 1;               // padded row stride (floats)

    __shared__ int rows[QTILE];
    extern __shared__ float lds[];        // QTILE x (f+1)

    if (t < QTILE) rows[t] = idx[(size_t)(qbase + t) * k + j];
    __syncthreads();

    // Stage: QTILE rows x f floats, float4 global loads, scalar LDS stores
    // (scalar stores keep the odd 513-float stride alignment-safe).
    const int f4 = f >> 2;                // float4s per row
    const int nvec = QTILE * f4;
    for (int lid = t; lid < nvec; lid += THREADS) {
        const int row = lid / f4;
        const int c4 = lid - row * f4;
        const float4 v = *reinterpret_cast<const float4*>(
            yd + (size_t)rows[row] * f + (c4 << 2));
        float* d = lds + row * ldst + (c4 << 2);
        d[0] = v.x; d[1] = v.y; d[2] = v.z; d[3] = v.w;
    }
    __syncthreads();

    // Transpose-write: oid = c*QTILE + q; lanes 0..15 share c, q contiguous.
    // out segment per (j,c): QTILE*4 = 64B, 64B-aligned. Fully coalesced.
    const size_t out_j = (size_t)j * f * m;
    const int ntot = QTILE * f;
    for (int oid = t; oid < ntot; oid += THREADS) {
        const int q = oid & (QTILE - 1);
        const int c = oid >> 4;           // log2(QTILE)
        out[out_j + (size_t)c * m + qbase + q] = lds[q * ldst + c];
    }
}

extern "C" void kernel_launch(void* const* d_in, const int* in_sizes, int n_in,
                              void* d_out, int out_size, void* d_ws, size_t ws_size,
                              hipStream_t stream) {
    // inputs: y_patch (m,64) f32 [unused except m], yd_patch (m,f) f32,
    //         idx_k (1,m,K) int
    const float* yd = (const float*)d_in[1];
    const int* idx = (const int*)d_in[2];
    float* out = (float*)d_out;

    const int m = in_sizes[0] / 64;
    const int f = in_sizes[1] / m;
    const int k = in_sizes[2] / m;

    dim3 grid(m / QTILE, k);
    const size_t lds_bytes = (size_t)QTILE * (f + 1) * sizeof(float);
    hipLaunchKernelGGL(gather_transpose_kernel, grid, dim3(THREADS), lds_bytes,
                       stream, yd, idx, out, m, f, k);
}

// Round 3
// 162.842 us; speedup vs baseline: 1.0152x; 1.0152x over previous
//
#include <hip/hip_runtime.h>

// out[(j*f + c)*m + q] = yd[idx[q*K + j]*f + c]
// m=8192, f=512, K=8, fp32. Memory-bound gather+transpose.
//
// Round 3: block tile = (j, C=32 cols, Q=256 rows).
//  - Stage: 256 gathered rows x 128B (one aligned full L2 line per row,
//    float4 coalesced loads).
//  - Write: per (j,c), 256 consecutive q = 1KB contiguous; each wave store
//    is 256B contiguous -> full-line writes only, no partial-line RMW and
//    no 64B/32KB-stride pathology (round-2 suspect at 165us).
//  - LDS [Q][C+1]: bank=(q+c)%32 -> <=2-way (free) on both phases. 34.8KB.

#define Q 256
#define C 32
#define THREADS 256

__global__ __launch_bounds__(THREADS) void gather_transpose_kernel(
    const float* __restrict__ yd, const int* __restrict__ idx,
    float* __restrict__ out, int m, int f, int k)
{
    const int qb = blockIdx.x * Q;          // q-tile base
    const int cb = blockIdx.y * C;          // column-tile base
    const int j  = blockIdx.z;              // neighbor index
    const int t  = threadIdx.x;

    __shared__ int rows[Q];
    __shared__ float lds[Q][C + 1];

    rows[t] = idx[(size_t)(qb + t) * k + j];
    __syncthreads();

    // Stage: Q rows x C floats (8 float4 chunks/row). Per wave: 8 rows x 8
    // chunks -> one full 128B line per row, coalesced.
    for (int lid = t; lid < Q * (C / 4); lid += THREADS) {
        const int row = lid >> 3;           // lid / (C/4)
        const int ch  = lid & 7;
        const float4 v = *reinterpret_cast<const float4*>(
            yd + (size_t)rows[row] * f + cb + (ch << 2));
        float* d = &lds[row][ch << 2];
        d[0] = v.x; d[1] = v.y; d[2] = v.z; d[3] = v.w;
    }
    __syncthreads();

    // Write: thread t <-> q = qb + t. Per c: 256 threads write 1KB contiguous
    // (each wave 256B contiguous, full lines). LDS read bank=(t+c)%32, free.
    float* p = out + (size_t)j * f * m + (size_t)cb * m + qb + t;
    #pragma unroll 8
    for (int c = 0; c < C; ++c) {
        p[(size_t)c * m] = lds[t][c];
    }
}

extern "C" void kernel_launch(void* const* d_in, const int* in_sizes, int n_in,
                              void* d_out, int out_size, void* d_ws, size_t ws_size,
                              hipStream_t stream) {
    // inputs: y_patch (m,64) f32 [only m used], yd_patch (m,f) f32,
    //         idx_k (1,m,K) int (staged as int32 by harness; absmax 0 in R2)
    const float* yd = (const float*)d_in[1];
    const int* idx = (const int*)d_in[2];
    float* out = (float*)d_out;

    const int m = in_sizes[0] / 64;
    const int f = in_sizes[1] / m;
    const int k = in_sizes[2] / m;

    dim3 grid(m / Q, f / C, k);
    hipLaunchKernelGGL(gather_transpose_kernel, grid, dim3(THREADS), 0,
                       stream, yd, idx, out, m, f, k);
}